// Round 2
// baseline (1672.873 us; speedup 1.0000x reference)
//
#include <hip/hip_runtime.h>

typedef __bf16 bf16x8 __attribute__((ext_vector_type(8)));
typedef float  f32x4  __attribute__((ext_vector_type(4)));

// out[C x R] (bf16) = in[R x C]^T (fp32) — tiny weight matrices only
__global__ void transpose_cvt(const float* __restrict__ in, __bf16* __restrict__ out,
                              int R, int Ccols) {
  int idx = blockIdx.x * 256 + threadIdx.x;
  if (idx < R * Ccols) {
    int r = idx / Ccols, c = idx % Ccols;
    out[(size_t)c * R + r] = (__bf16)in[(size_t)r * Ccols + c];
  }
}

// Load a bf16x8 A/B fragment from fp32 or bf16 source at element offset `off`.
template<bool F32>
__device__ inline bf16x8 load_frag(const void* __restrict__ base, size_t off) {
  if constexpr (F32) {
    const float* p = (const float*)base + off;
    f32x4 f0 = *(const f32x4*)p;
    f32x4 f1 = *(const f32x4*)(p + 4);
    bf16x8 r;
    r[0] = (__bf16)f0[0]; r[1] = (__bf16)f0[1]; r[2] = (__bf16)f0[2]; r[3] = (__bf16)f0[3];
    r[4] = (__bf16)f1[0]; r[5] = (__bf16)f1[1]; r[6] = (__bf16)f1[2]; r[7] = (__bf16)f1[3];
    return r;
  } else {
    return *(const bf16x8*)((const __bf16*)base + off);
  }
}

// C = A @ B (+bias)(relu?), A:[MxK] row-major (fp32 if AF32 else bf16),
// BT:[NxK] row-major bf16. C fp32 if CF32 else bf16.
// Block = 256 threads = 4 waves (2x2), wave = 4x4 subtiles of 16x16 -> 128x128 tile.
template<bool AF32, bool CF32>
__global__ __launch_bounds__(256) void gemm_bt_mfma(
    const void* __restrict__ A, int lda,
    const __bf16* __restrict__ BT, int ldbt,
    void* __restrict__ C, int ldc,
    const float* __restrict__ bias,
    int M, int N, int K, int do_relu, int transC)
{
  const int lane = threadIdx.x & 63;
  const int w    = threadIdx.x >> 6;
  const int wr   = w >> 1, wc = w & 1;
  const int quad = lane >> 4, l15 = lane & 15;

  const int mblk = blockIdx.x * 128;
  const int nblk = blockIdx.y * 128;

  // Fragment element offsets.
  // A frag: A[m = subtile_m + (lane&15)][k = kt + quad*8 + j], j=0..7 contiguous
  // B frag: BT[n = subtile_n + (lane&15)][k = kt + quad*8 + j]
  size_t aoff[4];
  const __bf16* bptr[4];
  #pragma unroll
  for (int i = 0; i < 4; ++i) {
    int m = mblk + wr * 64 + i * 16 + l15;
    if (m >= M) m = M - 1;              // clamp: safe load, store is guarded
    int n = nblk + wc * 64 + i * 16 + l15;
    if (n >= N) n = N - 1;
    aoff[i] = (size_t)m * lda + quad * 8;
    bptr[i] = BT + (size_t)n * ldbt + quad * 8;
  }

  f32x4 acc[4][4] = {};

  const int Kfull = K & ~31;
  for (int kt = 0; kt < Kfull; kt += 32) {
    bf16x8 af[4], bfr[4];
    #pragma unroll
    for (int i = 0; i < 4; ++i) af[i]  = load_frag<AF32>(A, aoff[i] + kt);
    #pragma unroll
    for (int i = 0; i < 4; ++i) bfr[i] = *(const bf16x8*)(bptr[i] + kt);
    #pragma unroll
    for (int i = 0; i < 4; ++i) {
      #pragma unroll
      for (int j = 0; j < 4; ++j) {
        acc[i][j] = __builtin_amdgcn_mfma_f32_16x16x32_bf16(af[i], bfr[j], acc[i][j], 0, 0, 0);
      }
    }
  }

  // K tail (K % 32 == 16 for K=10000): 8 | K so each quad's 8-group is all-valid
  // or all-invalid. Invalid quads re-load k=0 (in-bounds) then select zero.
  if (Kfull < K) {
    const bool kvalid = (Kfull + quad * 8 + 8) <= K;
    const size_t koff = kvalid ? (size_t)Kfull : 0;
    bf16x8 zf = {};
    bf16x8 af[4], bfr[4];
    #pragma unroll
    for (int i = 0; i < 4; ++i) {
      bf16x8 t = load_frag<AF32>(A, aoff[i] + koff);
      af[i] = kvalid ? t : zf;
    }
    #pragma unroll
    for (int i = 0; i < 4; ++i) {
      bf16x8 t = *(const bf16x8*)(bptr[i] + koff);
      bfr[i] = kvalid ? t : zf;
    }
    #pragma unroll
    for (int i = 0; i < 4; ++i) {
      #pragma unroll
      for (int j = 0; j < 4; ++j) {
        acc[i][j] = __builtin_amdgcn_mfma_f32_16x16x32_bf16(af[i], bfr[j], acc[i][j], 0, 0, 0);
      }
    }
  }

  // Epilogue. C/D layout: col = lane&15, row = quad*4 + r (verified m89/m91).
  #pragma unroll
  for (int j = 0; j < 4; ++j) {
    int col = nblk + wc * 64 + j * 16 + l15;
    if (col >= N) continue;
    float bv = bias ? bias[col] : 0.0f;
    #pragma unroll
    for (int i = 0; i < 4; ++i) {
      int rowb = mblk + wr * 64 + i * 16 + quad * 4;
      #pragma unroll
      for (int r = 0; r < 4; ++r) {
        int row = rowb + r;
        if (row < M) {
          float v = acc[i][j][r] + bv;
          if (do_relu) v = v > 0.0f ? v : 0.0f;
          size_t idx = transC ? ((size_t)col * ldc + row) : ((size_t)row * ldc + col);
          if constexpr (CF32) ((float*)C)[idx]   = v;
          else                ((__bf16*)C)[idx] = (__bf16)v;
        }
      }
    }
  }
}

extern "C" void kernel_launch(void* const* d_in, const int* in_sizes, int n_in,
                              void* d_out, int out_size, void* d_ws, size_t ws_size,
                              hipStream_t stream) {
  const float* x   = (const float*)d_in[0];  // [10000 x 512]
  const float* adj = (const float*)d_in[1];  // [10000 x 10000]
  const float* W1  = (const float*)d_in[2];  // [512 x 128]
  const float* b1  = (const float*)d_in[3];  // [128]
  const float* W2  = (const float*)d_in[4];  // [128 x 512]
  const float* b2  = (const float*)d_in[5];  // [512]
  float* out = (float*)d_out;                // [10000 x 512]

  const int Nn = 10000, NF = 512, NH = 128;

  // Workspace layout (bf16 intermediates, ~15.6 MB total)
  char* ws = (char*)d_ws;
  __bf16* W1T = (__bf16*)(ws);                               // [128][512]
  __bf16* W2T = (__bf16*)(ws + 131072);                      // [512][128]
  __bf16* xwT = (__bf16*)(ws + 262144);                      // [128][10000]
  __bf16* h   = (__bf16*)(ws + 262144 + 2560000);            // [10000][128]
  __bf16* hwT = (__bf16*)(ws + 262144 + 2 * 2560000);        // [512][10000]

  hipLaunchKernelGGL(transpose_cvt, dim3(256), dim3(256), 0, stream, W1, W1T, NF, NH);
  hipLaunchKernelGGL(transpose_cvt, dim3(256), dim3(256), 0, stream, W2, W2T, NH, NF);

  dim3 blk(256);
  const int MB = (Nn + 127) / 128;  // 79

  // K1: xwT = (x @ W1)^T          M=10000 N=128 K=512   A=fp32 -> C=bf16 (transposed)
  hipLaunchKernelGGL((gemm_bt_mfma<true, false>), dim3(MB, 1), blk, 0, stream,
                     (const void*)x, NF, W1T, NF, (void*)xwT, Nn, (const float*)nullptr,
                     Nn, NH, NF, 0, 1);
  // K2: h = relu(adj @ xw + b1)   M=10000 N=128 K=10000 A=fp32 -> C=bf16
  hipLaunchKernelGGL((gemm_bt_mfma<true, false>), dim3(MB, 1), blk, 0, stream,
                     (const void*)adj, Nn, xwT, Nn, (void*)h, NH, b1,
                     Nn, NH, Nn, 1, 0);
  // K3: hwT = (h @ W2)^T          M=10000 N=512 K=128   A=bf16 -> C=bf16 (transposed)
  hipLaunchKernelGGL((gemm_bt_mfma<false, false>), dim3(MB, 4), blk, 0, stream,
                     (const void*)h, NH, W2T, NH, (void*)hwT, Nn, (const float*)nullptr,
                     Nn, NF, NH, 0, 1);
  // K4: out = adj @ hw + b2       M=10000 N=512 K=10000 A=fp32 -> C=fp32
  hipLaunchKernelGGL((gemm_bt_mfma<true, true>), dim3(MB, 4), blk, 0, stream,
                     (const void*)adj, Nn, hwT, Nn, (void*)out, NF, b2,
                     Nn, NF, Nn, 0, 0);
}

// Round 3
// 781.918 us; speedup vs baseline: 2.1394x; 2.1394x over previous
//
#include <hip/hip_runtime.h>
#include <stdint.h>

typedef __bf16 bf16x8 __attribute__((ext_vector_type(8)));
typedef float  f32x4  __attribute__((ext_vector_type(4)));

// async 16B global -> LDS (dest = wave-uniform base + lane*16)
__device__ __forceinline__ void gl_lds16(const void* g, void* l) {
  __builtin_amdgcn_global_load_lds(
      (const __attribute__((address_space(1))) void*)g,
      (__attribute__((address_space(3))) void*)l, 16, 0, 0);
}

// out[C x R] (bf16) = in[R x C]^T (fp32) — tiny weight matrices only
__global__ void transpose_cvt(const float* __restrict__ in, __bf16* __restrict__ out,
                              int R, int Ccols) {
  int idx = blockIdx.x * 256 + threadIdx.x;
  if (idx < R * Ccols) {
    int r = idx / Ccols, c = idx % Ccols;
    out[(size_t)c * R + r] = (__bf16)in[(size_t)r * Ccols + c];
  }
}

// Sum S split-K fp32 slabs (each MN elems), + optional bias (col = idx&127) /
// relu, write bf16 either row-major (out[idx]) or transposed (out[col*ldT+row]).
__global__ void reduce_sk(const float* __restrict__ P, int S, int MN,
                          const float* __restrict__ bias, __bf16* __restrict__ out,
                          int do_relu, int transT, int ldT) {
  int idx = blockIdx.x * 256 + threadIdx.x;
  if (idx >= MN) return;
  float v = 0.0f;
  for (int s = 0; s < S; ++s) v += P[(size_t)s * MN + idx];
  int col = idx & 127, row = idx >> 7;
  if (bias) v += bias[col];
  if (do_relu && v < 0.0f) v = 0.0f;
  if (transT) out[(size_t)col * ldT + row] = (__bf16)v;
  else        out[idx] = (__bf16)v;
}

// C = A @ B, A:[MxK] (fp32 if AF32 else bf16) row-major, BT:[NxK] bf16 row-major.
// 256 thr = 4 waves (2x2), wave = 4x4 of 16x16x32 MFMA -> 128x128 tile, BK=32.
// LDS staged via global_load_lds w/ XOR-swizzled source units (reads ~conflict-free).
// MODE 0: store fp32 partial slab at C + blockIdx.z*M*N (split-K).
// MODE 1: final bf16 (+bias/relu, optional transC). MODE 2: final fp32 (+bias).
template<bool AF32, int MODE>
__global__ __launch_bounds__(256) void gemm_sk(
    const void* __restrict__ A, int lda,
    const __bf16* __restrict__ BT, int ldbt,
    void* __restrict__ C, int ldc,
    const float* __restrict__ bias,
    int M, int N, int K, int kchunk, int do_relu, int transC)
{
  constexpr int ABYTES = AF32 ? 16384 : 8192;
  __shared__ char smem[ABYTES + 8192];
  char* sA = smem;
  char* sB = smem + ABYTES;

  const int tid  = threadIdx.x;
  const int lane = tid & 63;
  const int w    = tid >> 6;
  const int wr = w >> 1, wc = w & 1;
  const int quad = lane >> 4, l15 = lane & 15;

  const int mblk = blockIdx.x * 128;
  const int nblk = blockIdx.y * 128;
  const int kbeg = blockIdx.z * kchunk;
  int kend = kbeg + kchunk; if (kend > K) kend = K;

  f32x4 acc[4][4] = {};

  for (int kt = kbeg; kt < kend; kt += 32) {
    const int klen = (kend - kt) < 32 ? (kend - kt) : 32;
    __syncthreads();   // prior iter's LDS reads done before overwrite
    // ---- stage A tile: [128][32] (fp32: row=128B=8 units / bf16: row=64B=4 units)
    if (AF32) {
      const float* Af = (const float*)A;
      #pragma unroll
      for (int t = 0; t < 4; ++t) {
        int slot = (w * 4 + t) * 64 + lane;          // 1024 slots
        int row = slot >> 3, p = slot & 7;
        int u = p ^ (row & 7);                       // swizzled source unit
        int rg = mblk + row; if (rg >= M) rg = M - 1;
        int ku = (u * 4 + 4 <= klen) ? (kt + u * 4) : kt;  // clamp tail (zeroed later)
        gl_lds16(Af + (size_t)rg * lda + ku, sA + slot * 16);
      }
    } else {
      const __bf16* Ab = (const __bf16*)A;
      #pragma unroll
      for (int t = 0; t < 2; ++t) {
        int slot = (w * 2 + t) * 64 + lane;          // 512 slots
        int row = slot >> 2, p = slot & 3;
        int u = p ^ (row & 3);
        int rg = mblk + row; if (rg >= M) rg = M - 1;
        int ku = (u * 8 + 8 <= klen) ? (kt + u * 8) : kt;
        gl_lds16(Ab + (size_t)rg * lda + ku, sA + slot * 16);
      }
    }
    // ---- stage B tile: [128][32] bf16
    #pragma unroll
    for (int t = 0; t < 2; ++t) {
      int slot = (w * 2 + t) * 64 + lane;
      int row = slot >> 2, p = slot & 3;
      int u = p ^ (row & 3);
      int rg = nblk + row; if (rg >= N) rg = N - 1;
      int ku = (u * 8 + 8 <= klen) ? (kt + u * 8) : kt;
      gl_lds16(BT + (size_t)rg * ldbt + ku, sB + slot * 16);
    }
    __syncthreads();   // drains vmcnt -> staged data visible

    // ---- fragments (un-swizzle on read) ----
    bf16x8 af[4], bfr[4];
    #pragma unroll
    for (int i = 0; i < 4; ++i) {
      int mloc = wr * 64 + i * 16 + l15;
      if (AF32) {
        int u0 = quad * 2, u1 = u0 + 1;
        f32x4 lo = *(const f32x4*)(sA + mloc * 128 + ((u0 ^ (mloc & 7)) * 16));
        f32x4 hi = *(const f32x4*)(sA + mloc * 128 + ((u1 ^ (mloc & 7)) * 16));
        bf16x8 r;
        r[0] = (__bf16)lo[0]; r[1] = (__bf16)lo[1]; r[2] = (__bf16)lo[2]; r[3] = (__bf16)lo[3];
        r[4] = (__bf16)hi[0]; r[5] = (__bf16)hi[1]; r[6] = (__bf16)hi[2]; r[7] = (__bf16)hi[3];
        af[i] = r;
      } else {
        af[i] = *(const bf16x8*)(sA + mloc * 64 + ((quad ^ (mloc & 3)) * 16));
      }
    }
    #pragma unroll
    for (int j = 0; j < 4; ++j) {
      int nloc = wc * 64 + j * 16 + l15;
      bfr[j] = *(const bf16x8*)(sB + nloc * 64 + ((quad ^ (nloc & 3)) * 16));
    }
    if (klen < 32) {                 // K tail (klen==16): quads 2,3 hold garbage -> zero A side
      bf16x8 z = {};
      if (quad * 8 + 8 > klen) {
        #pragma unroll
        for (int i = 0; i < 4; ++i) af[i] = z;
      }
    }
    #pragma unroll
    for (int i = 0; i < 4; ++i)
      #pragma unroll
      for (int j = 0; j < 4; ++j)
        acc[i][j] = __builtin_amdgcn_mfma_f32_16x16x32_bf16(af[i], bfr[j], acc[i][j], 0, 0, 0);
  }

  // ---- epilogue. C/D layout: col = lane&15, row = quad*4 + r ----
  if (MODE == 0) {
    float* P = (float*)C + (size_t)blockIdx.z * ((size_t)M * N);
    #pragma unroll
    for (int j = 0; j < 4; ++j) {
      int col = nblk + wc * 64 + j * 16 + l15;
      #pragma unroll
      for (int i = 0; i < 4; ++i) {
        int rowb = mblk + wr * 64 + i * 16 + quad * 4;
        #pragma unroll
        for (int r = 0; r < 4; ++r) {
          int row = rowb + r;
          if (row < M) P[(size_t)row * N + col] = acc[i][j][r];
        }
      }
    }
  } else {
    #pragma unroll
    for (int j = 0; j < 4; ++j) {
      int col = nblk + wc * 64 + j * 16 + l15;
      float bv = bias ? bias[col] : 0.0f;
      #pragma unroll
      for (int i = 0; i < 4; ++i) {
        int rowb = mblk + wr * 64 + i * 16 + quad * 4;
        #pragma unroll
        for (int r = 0; r < 4; ++r) {
          int row = rowb + r;
          if (row < M) {
            float v = acc[i][j][r] + bv;
            if (do_relu && v < 0.0f) v = 0.0f;
            size_t idx = transC ? ((size_t)col * ldc + row) : ((size_t)row * ldc + col);
            if (MODE == 1) ((__bf16*)C)[idx] = (__bf16)v;
            else           ((float*)C)[idx] = v;
          }
        }
      }
    }
  }
}

extern "C" void kernel_launch(void* const* d_in, const int* in_sizes, int n_in,
                              void* d_out, int out_size, void* d_ws, size_t ws_size,
                              hipStream_t stream) {
  const float* x   = (const float*)d_in[0];  // [10000 x 512]
  const float* adj = (const float*)d_in[1];  // [10000 x 10000]
  const float* W1  = (const float*)d_in[2];  // [512 x 128]
  const float* b1  = (const float*)d_in[3];  // [128]
  const float* W2  = (const float*)d_in[4];  // [128 x 512]
  const float* b2  = (const float*)d_in[5];  // [512]
  float* out = (float*)d_out;                // [10000 x 512]

  const int Nn = 10000, NF = 512, NH = 128;
  const size_t MN = (size_t)Nn * NH;         // 1,280,000

  // ws layout (bytes)
  char* ws = (char*)d_ws;
  __bf16* W1T = (__bf16*)(ws + 0);           // [128][512]   131072
  __bf16* W2T = (__bf16*)(ws + 131072);      // [512][128]   131072
  __bf16* xwT = (__bf16*)(ws + 262144);      // [128][10000] 2560000
  __bf16* hT  = (__bf16*)(ws + 2822144);     // [128][10000] 2560000
  __bf16* ah  = (__bf16*)(ws + 5382144);     // [10000][128] 2560000
  float*  P   = (float*)(ws + 7942144);      // [S][10000][128] fp32

  // split-K factor sized to available workspace (constant across calls)
  size_t slab = MN * sizeof(float);
  long avail = (long)((ws_size - 7942144) / slab);
  int S = avail < 1 ? 1 : (avail > 8 ? 8 : (int)avail);
  int kchunk = ((Nn + S - 1) / S + 31) & ~31;
  int Sz = (Nn + kchunk - 1) / kchunk;       // actual #slices

  dim3 blk(256);
  const int MB = (Nn + 127) / 128;           // 79

  hipLaunchKernelGGL(transpose_cvt, dim3((NF * NH + 255) / 256), blk, 0, stream, W1, W1T, NF, NH);
  hipLaunchKernelGGL(transpose_cvt, dim3((NF * NH + 255) / 256), blk, 0, stream, W2, W2T, NH, NF);

  // K1: xwT = (x @ W1)^T        M=10000 N=128 K=512, A fp32 -> bf16 transC
  hipLaunchKernelGGL((gemm_sk<true, 1>), dim3(MB, 1, 1), blk, 0, stream,
                     (const void*)x, NF, W1T, NF, (void*)xwT, Nn, (const float*)nullptr,
                     Nn, NH, NF, NF, 0, 1);
  // K2: P = split-K(adj @ xw)   M=10000 N=128 K=10000
  hipLaunchKernelGGL((gemm_sk<true, 0>), dim3(MB, 1, Sz), blk, 0, stream,
                     (const void*)adj, Nn, xwT, Nn, (void*)P, NH, (const float*)nullptr,
                     Nn, NH, Nn, kchunk, 0, 0);
  //     hT = relu(sum P + b1)^T
  hipLaunchKernelGGL(reduce_sk, dim3(((int)MN + 255) / 256), blk, 0, stream,
                     P, Sz, (int)MN, b1, hT, 1, 1, Nn);
  // K3: P = split-K(adj @ h)    M=10000 N=128 K=10000
  hipLaunchKernelGGL((gemm_sk<true, 0>), dim3(MB, 1, Sz), blk, 0, stream,
                     (const void*)adj, Nn, hT, Nn, (void*)P, NH, (const float*)nullptr,
                     Nn, NH, Nn, kchunk, 0, 0);
  //     ah = sum P              [10000][128] bf16
  hipLaunchKernelGGL(reduce_sk, dim3(((int)MN + 255) / 256), blk, 0, stream,
                     P, Sz, (int)MN, (const float*)nullptr, ah, 0, 0, 0);
  // K4: out = ah @ W2 + b2      M=10000 N=512 K=128, fp32 out
  hipLaunchKernelGGL((gemm_sk<false, 2>), dim3(MB, 4, 1), blk, 0, stream,
                     (const void*)ah, NH, W2T, NH, (void*)out, NF, b2,
                     Nn, NF, NH, NH, 0, 0);
}